// Round 6
// baseline (318.306 us; speedup 1.0000x reference)
//
#include <hip/hip_runtime.h>

typedef unsigned short u16;
typedef _Float16 h8 __attribute__((ext_vector_type(8)));
typedef __fp16 fp16x2 __attribute__((ext_vector_type(2)));
typedef float f32x4 __attribute__((ext_vector_type(4)));

constexpr int B_ = 4, S_ = 2048, D_ = 1024, H_ = 16;

// async global->LDS, 16B per lane; LDS dest = (wave-uniform base) + lane*16
__device__ __forceinline__ void async16(const void* g, void* l) {
  __builtin_amdgcn_global_load_lds(
      (const __attribute__((address_space(1))) void*)g,
      (__attribute__((address_space(3))) void*)l, 16, 0, 0);
}

// pack two f32 -> fp16x2 (RTZ) as a raw uint
__device__ __forceinline__ unsigned pk2(float a, float b) {
  union { fp16x2 h; unsigned u; } c;
  c.h = __builtin_amdgcn_cvt_pkrtz(a, b);
  return c.u;
}

// raw hardware exp2 (v_exp_f32), no ln2 multiply
__device__ __forceinline__ float fexp2(float x) {
#if __has_builtin(__builtin_amdgcn_exp2f)
  return __builtin_amdgcn_exp2f(x);
#else
  return exp2f(x);
#endif
}

// log2(e)/8: folded into the Q columns of the QKV GEMM epilogue (f32, before
// the single fp16 rounding -> same error structure as the exact-1/8 path).
#define QSCALE 0.18033688011112042f

// ---------------------------------------------------------------------------
// fp32 -> fp16 convert for all three tensors in ONE launch.
// Region split by blockIdx: x [0,8192), wi [8192,11264), wo [11264,12288).
// ---------------------------------------------------------------------------
__global__ __launch_bounds__(256) void cvt3_kernel(
    const float* __restrict__ x, const float* __restrict__ wi,
    const float* __restrict__ wo, _Float16* __restrict__ xh,
    _Float16* __restrict__ wih, _Float16* __restrict__ woh)
{
  const int bid = blockIdx.x;
  const float* src;
  _Float16* dst;
  int base;
  if (bid < 8192)       { src = x;  dst = xh;  base = bid; }
  else if (bid < 11264) { src = wi; dst = wih; base = bid - 8192; }
  else                  { src = wo; dst = woh; base = bid - 11264; }
  const int i = (base * 256 + threadIdx.x) * 4;
  const float4 v = *(const float4*)(src + i);
  uint2 o;
  o.x = pk2(v.x, v.y);
  o.y = pk2(v.z, v.w);
  *(uint2*)(dst + i) = o;
}

// ---------------------------------------------------------------------------
// 128x128x64 phase-pipelined GEMM. C = A Bw^T + bias.
// 256 threads = 4 waves (2x2), wave tile 64x64, acc[4][4] f32x4.
// LDS 64 KiB (2 x 16 KiB double-buffered per operand) -> 2 BLOCKS/CU: the
// two blocks' barriers are independent, so one block's MFMA covers the
// other's LDS/barrier stalls (2 waves/SIMD lockstep was the 22%-MfmaUtil
// ceiling of the 1-block/CU 256-row template).
// Frag-major LDS (measured 0 bank conflicts): frag-block (t,kk) at
// (t*2+kk)*512 halves; lane l holds row (l&15), k-sub (l>>4).
//
// UNIFORM PHASES (2 per K-tile, one per kk half-tile), m201-style:
//   vmcnt(8) -> barrier -> 8x ds_read_b128 -> stage freed half-tile
//   (4 gload_lds) -> setprio(1) 16 MFMA setprio(0)
// Stage at phase P fills phase P+3's region (the one freed at P-1), so every
// load has ~3 phases (~600 cyc) of cover; vmcnt counted at 8 (3 stages in
// flight), 4/0 only in the last two phases. One barrier per phase.
// ---------------------------------------------------------------------------
template<bool OUT_HALF, bool SCALE_Q>
__global__ __launch_bounds__(256, 2) void gemm128p_f16(
    const _Float16* __restrict__ A, const _Float16* __restrict__ Bw,
    const float* __restrict__ bias, void* __restrict__ Cout,
    int M, int N, int K)
{
  __shared__ __align__(16) _Float16 sA[2][8192];
  __shared__ __align__(16) _Float16 sB[2][8192];

  const int tid = threadIdx.x;
  const int lane = tid & 63, w = tid >> 6;  // 4 waves
  const int wm = w & 1, wn = w >> 1;        // 2 x 2 wave grid

  // XCD-bijective swizzle (gridDim.x % 8 == 0)
  const int id = blockIdx.x;
  const int cpx = gridDim.x >> 3;
  const int swz = (id & 7) * cpx + (id >> 3);
  const int nbx = N >> 7;
  const int bx = swz % nbx, by = swz / nbx;
  const int m0 = by * 128, n0 = bx * 128;

  // Staging map: wave w, load j in {0,1} covers m/n-subtile t = w + 4j.
  const int r15 = lane & 15, s4 = lane >> 4;
  const int tA0 = w, tA1 = w + 4;
  const _Float16* gA0 = A + (size_t)(m0 + 16 * tA0 + r15) * K + s4 * 8;
  const _Float16* gA1 = A + (size_t)(m0 + 16 * tA1 + r15) * K + s4 * 8;
  const _Float16* gB0 = Bw + (size_t)(n0 + 16 * tA0 + r15) * K + s4 * 8;
  const _Float16* gB1 = Bw + (size_t)(n0 + 16 * tA1 + r15) * K + s4 * 8;

  // stage one kk half-tile (A+B) of tile `tile` into buffer bq: 4 loads
  auto stage = [&](int tile, int kk, int bq) {
    const int ko = tile * 64 + kk * 32;
    async16(gA0 + ko, &sA[bq][(tA0 * 2 + kk) * 512]);
    async16(gA1 + ko, &sA[bq][(tA1 * 2 + kk) * 512]);
    async16(gB0 + ko, &sB[bq][(tA0 * 2 + kk) * 512]);
    async16(gB1 + ko, &sB[bq][(tA1 * 2 + kk) * 512]);
  };

  const f32x4 zf = {0.f, 0.f, 0.f, 0.f};
  f32x4 acc[4][4];
#pragma unroll
  for (int i = 0; i < 4; ++i)
#pragma unroll
    for (int j = 0; j < 4; ++j) acc[i][j] = zf;

  const int NT = K >> 6;  // 16 for K=1024

  // prologue: regions for phases 0,1,2 (tile0 kk0, tile0 kk1, tile1 kk0)
  stage(0, 0, 0);
  stage(0, 1, 0);
  stage(1, 0, 1);

#define VM8 asm volatile("s_waitcnt vmcnt(8)" ::: "memory")
#define VM4 asm volatile("s_waitcnt vmcnt(4)" ::: "memory")
#define VM0 asm volatile("s_waitcnt vmcnt(0)" ::: "memory")
#define FENCE asm volatile("" ::: "memory")

  for (int T = 0; T < NT; ++T) {
    const int buf = T & 1;
    const bool lastT = (T == NT - 1);

    // ================= phase (T, kk=0)  [P = 2T] =================
    if (!lastT) { VM8; } else { VM4; }
    __builtin_amdgcn_s_barrier();
    FENCE;
    {
      h8 fa[4], fb[4];
#pragma unroll
      for (int i = 0; i < 4; ++i) {
        fa[i] = *(const h8*)&sA[buf][((wm * 4 + i) * 2 + 0) * 512 + lane * 8];
        fb[i] = *(const h8*)&sB[buf][((wn * 4 + i) * 2 + 0) * 512 + lane * 8];
      }
      if (T + 1 < NT) stage(T + 1, 1, (T + 1) & 1);  // region freed at P-1
      __builtin_amdgcn_s_setprio(1);
#pragma unroll
      for (int i = 0; i < 4; ++i)
#pragma unroll
        for (int j = 0; j < 4; ++j)
          acc[i][j] = __builtin_amdgcn_mfma_f32_16x16x32_f16(fa[i], fb[j], acc[i][j], 0, 0, 0);
      __builtin_amdgcn_s_setprio(0);
    }

    // ================= phase (T, kk=1)  [P = 2T+1] =================
    if (!lastT) { VM8; } else { VM0; }
    __builtin_amdgcn_s_barrier();
    FENCE;
    {
      h8 fa[4], fb[4];
#pragma unroll
      for (int i = 0; i < 4; ++i) {
        fa[i] = *(const h8*)&sA[buf][((wm * 4 + i) * 2 + 1) * 512 + lane * 8];
        fb[i] = *(const h8*)&sB[buf][((wn * 4 + i) * 2 + 1) * 512 + lane * 8];
      }
      if (T + 2 < NT) stage(T + 2, 0, buf);  // region freed at P-1 (write-behind)
      __builtin_amdgcn_s_setprio(1);
#pragma unroll
      for (int i = 0; i < 4; ++i)
#pragma unroll
        for (int j = 0; j < 4; ++j)
          acc[i][j] = __builtin_amdgcn_mfma_f32_16x16x32_f16(fa[i], fb[j], acc[i][j], 0, 0, 0);
      __builtin_amdgcn_s_setprio(0);
    }
  }

#undef VM8
#undef VM4
#undef VM0
#undef FENCE

  // ---- epilogue
  const int g = lane >> 4, cc = lane & 15;
#pragma unroll
  for (int j = 0; j < 4; ++j) {
    const int col = n0 + (wn * 4 + j) * 16 + cc;
    const float bv = bias[col];
    float qs = 1.0f;
    if constexpr (SCALE_Q) qs = (col < 1024) ? QSCALE : 1.0f;
#pragma unroll
    for (int i = 0; i < 4; ++i) {
      const int rowb = m0 + (wm * 4 + i) * 16 + g * 4;
#pragma unroll
      for (int r = 0; r < 4; ++r) {
        float v = acc[i][j][r] + bv;
        if constexpr (SCALE_Q) v *= qs;
        if constexpr (OUT_HALF)
          ((_Float16*)Cout)[(size_t)(rowb + r) * N + col] = (_Float16)v;
        else
          ((float*)Cout)[(size_t)(rowb + r) * N + col] = v;
      }
    }
  }
}

// ---------------------------------------------------------------------------
// V transpose: qkv fp16 [B,S,3D] (V at col 2048+h*64+d) -> vT [(b,h,d)][S]
// ---------------------------------------------------------------------------
__global__ __launch_bounds__(256) void transpose_v(
    const u16* __restrict__ qkv, u16* __restrict__ vT)
{
  __shared__ u16 T[64 * 73];
  const int tid = threadIdx.x;
  const int bh = blockIdx.y, s0 = blockIdx.x * 64;
  const int b = bh >> 4, h = bh & 15;
#pragma unroll
  for (int t = 0; t < 2; ++t) {
    const int c = tid + t * 256, r = c >> 3, cs = c & 7;
    union { int4 v; u16 s[8]; } u;
    u.v = *(const int4*)(qkv + (size_t)(b * S_ + s0 + r) * 3072 + 2048 + h * 64 + 8 * cs);
#pragma unroll
    for (int i = 0; i < 8; ++i) T[r * 73 + 8 * cs + i] = u.s[i];
  }
  __syncthreads();
#pragma unroll
  for (int t = 0; t < 2; ++t) {
    const int c = tid + t * 256, rd = c >> 3, ss = c & 7;
    union { int4 v; u16 s[8]; } u;
#pragma unroll
    for (int i = 0; i < 8; ++i) u.s[i] = T[(8 * ss + i) * 73 + rd];
    *(int4*)(vT + (size_t)(bh * 64 + rd) * S_ + s0 + 8 * ss) = u.v;
  }
}

// ---------------------------------------------------------------------------
// Flash attention fp16. Block = 128 q-rows of one (b,h), 4 waves, wave owns
// 32 q (m=2 tiles). S^T via mfma(kf,qf); sP aliases sQ. K/V/Q staged with
// global_load_lds width 16. LDS 34 KiB -> 4 blocks/CU.
// Q arrives PRE-SCALED by log2(e)/8 (GEMM epilogue) -> P = exp2(S) with raw
// v_exp_f32, no per-score multiply. setprio(1) around MFMA clusters.
// ---------------------------------------------------------------------------
__global__ __launch_bounds__(256, 4) void attn_f16(
    const _Float16* __restrict__ qkv, const _Float16* __restrict__ vT,
    _Float16* __restrict__ attnO, const int* __restrict__ causal_ptr)
{
  __shared__ __align__(16) _Float16 sQP[9216];  // Q staging, then P (4w x 32 x 72)
  __shared__ __align__(16) _Float16 sK[4096];
  __shared__ __align__(16) _Float16 sV[4096];

  const int tid = threadIdx.x, lane = tid & 63, w = tid >> 6;
  const int q4 = lane >> 4, cc = lane & 15;
  const int bh = blockIdx.y, b = bh >> 4, h = bh & 15;
  const int q0 = blockIdx.x * 128;
  const int causal = causal_ptr[0];

  {
    const int rr = lane & 15, sc8 = lane >> 4;
#pragma unroll
    for (int tt = 0; tt < 2; ++tt) {
      const int t = 2 * w + tt;
#pragma unroll
      for (int sh = 0; sh < 2; ++sh) {
        const _Float16* g = qkv + (size_t)(b * S_ + q0 + 16 * t + rr) * 3072 + h * 64 + 8 * (4 * sh + sc8);
        async16(g, &sQP[t * 1024 + sh * 512]);
      }
    }
  }
  __syncthreads();  // Q landed

  // Q frags (already carry the log2(e)/8 score scale from the GEMM epilogue)
  h8 qf[2][2];
#pragma unroll
  for (int m = 0; m < 2; ++m)
#pragma unroll
    for (int kk = 0; kk < 2; ++kk)
      qf[m][kk] = *(const h8*)&sQP[((2 * w + m) << 10) + (kk << 9) + (lane << 3)];

  h8 ones;
#pragma unroll
  for (int i = 0; i < 8; ++i) ones[i] = (_Float16)1.0f;

  const _Float16* gK = qkv + (size_t)(b * S_ + 16 * w + (lane & 15)) * 3072 + 1024 + h * 64 + 8 * (lane >> 4);
  const _Float16* gV = vT + (size_t)(bh * 64 + 16 * w + (lane & 15)) * S_ + 8 * (lane >> 4);
  _Float16* lK0 = &sK[w * 1024];
  _Float16* lV0 = &sV[w * 1024];

  const int wp = w * 2304;

  const f32x4 zf = {0.f, 0.f, 0.f, 0.f};
  f32x4 oa[2][4], lac[2];
#pragma unroll
  for (int m = 0; m < 2; ++m) {
    lac[m] = zf;
#pragma unroll
    for (int nt = 0; nt < 4; ++nt) oa[m][nt] = zf;
  }

  for (int j0 = 0; j0 < S_; j0 += 64) {
    if (causal && j0 > q0 + 127) break;
    __syncthreads();
    async16(gK + (size_t)j0 * 3072, lK0);
    async16(gK + (size_t)j0 * 3072 + 32, lK0 + 512);
    async16(gV + j0, lV0);
    async16(gV + j0 + 32, lV0 + 512);
    __syncthreads();

    f32x4 sc[2][4];
    __builtin_amdgcn_s_setprio(1);
#pragma unroll
    for (int nt = 0; nt < 4; ++nt) {
      const h8 kf0 = *(const h8*)&sK[(nt << 10) + (lane << 3)];
      const h8 kf1 = *(const h8*)&sK[(nt << 10) + 512 + (lane << 3)];
#pragma unroll
      for (int m = 0; m < 2; ++m) {
        sc[m][nt] = __builtin_amdgcn_mfma_f32_16x16x32_f16(kf0, qf[m][0], zf, 0, 0, 0);
        sc[m][nt] = __builtin_amdgcn_mfma_f32_16x16x32_f16(kf1, qf[m][1], sc[m][nt], 0, 0, 0);
      }
    }
    __builtin_amdgcn_s_setprio(0);

    if (causal) {
#pragma unroll
      for (int m = 0; m < 2; ++m)
#pragma unroll
        for (int nt = 0; nt < 4; ++nt)
#pragma unroll
          for (int r = 0; r < 4; ++r)
            if ((j0 + nt * 16 + q4 * 4 + r) > (q0 + 32 * w + m * 16 + cc))
              sc[m][nt][r] = -1.0e30f;
    }

    // P = exp2(S): scores arrive in log2 units; raw v_exp_f32, no multiply
#pragma unroll
    for (int m = 0; m < 2; ++m)
#pragma unroll
      for (int nt = 0; nt < 4; ++nt) {
        uint2 pk;
        pk.x = pk2(fexp2(sc[m][nt][0]), fexp2(sc[m][nt][1]));
        pk.y = pk2(fexp2(sc[m][nt][2]), fexp2(sc[m][nt][3]));
        *(uint2*)&sQP[wp + (m * 16 + cc) * 72 + nt * 16 + q4 * 4] = pk;
      }

    asm volatile("s_waitcnt lgkmcnt(0)" ::: "memory");

    h8 pf[2][2];
#pragma unroll
    for (int m = 0; m < 2; ++m)
#pragma unroll
      for (int kk = 0; kk < 2; ++kk)
        pf[m][kk] = *(const h8*)&sQP[wp + (m * 16 + cc) * 72 + kk * 32 + q4 * 8];

    __builtin_amdgcn_s_setprio(1);
#pragma unroll
    for (int m = 0; m < 2; ++m) {
      lac[m] = __builtin_amdgcn_mfma_f32_16x16x32_f16(pf[m][0], ones, lac[m], 0, 0, 0);
      lac[m] = __builtin_amdgcn_mfma_f32_16x16x32_f16(pf[m][1], ones, lac[m], 0, 0, 0);
    }
#pragma unroll
    for (int nt = 0; nt < 4; ++nt) {
      const h8 vf0 = *(const h8*)&sV[(nt << 10) + (lane << 3)];
      const h8 vf1 = *(const h8*)&sV[(nt << 10) + 512 + (lane << 3)];
#pragma unroll
      for (int m = 0; m < 2; ++m) {
        oa[m][nt] = __builtin_amdgcn_mfma_f32_16x16x32_f16(pf[m][0], vf0, oa[m][nt], 0, 0, 0);
        oa[m][nt] = __builtin_amdgcn_mfma_f32_16x16x32_f16(pf[m][1], vf1, oa[m][nt], 0, 0, 0);
      }
    }
    __builtin_amdgcn_s_setprio(0);
  }

#pragma unroll
  for (int m = 0; m < 2; ++m) {
    float inv[4];
#pragma unroll
    for (int r = 0; r < 4; ++r) inv[r] = 1.0f / lac[m][r];
#pragma unroll
    for (int nt = 0; nt < 4; ++nt) {
      const int col = h * 64 + nt * 16 + cc;
#pragma unroll
      for (int r = 0; r < 4; ++r) {
        const int row = b * S_ + q0 + 32 * w + m * 16 + q4 * 4 + r;
        attnO[(size_t)row * D_ + col] = (_Float16)(oa[m][nt][r] * inv[r]);
      }
    }
  }
}

// ---------------------------------------------------------------------------
extern "C" void kernel_launch(void* const* d_in, const int* in_sizes, int n_in,
                              void* d_out, int out_size, void* d_ws, size_t ws_size,
                              hipStream_t stream)
{
  const float* x  = (const float*)d_in[0];
  const float* wi = (const float*)d_in[1];
  const float* bi = (const float*)d_in[2];
  const float* wo = (const float*)d_in[3];
  const float* bo = (const float*)d_in[4];
  const int* causal = (const int*)d_in[5];

  _Float16* xh   = (_Float16*)d_ws;       // 8192*1024
  _Float16* wih  = xh + 8388608;          // 3072*1024
  _Float16* woh  = wih + 3145728;         // 1024*1024
  _Float16* qkvb = woh + 1048576;         // 8192*3072
  _Float16* vT   = qkvb + 25165824;       // 4096*2048
  _Float16* attn = vT + 8388608;          // 8192*1024

  const int M = B_ * S_;  // 8192

  cvt3_kernel<<<12288, 256, 0, stream>>>(x, wi, wo, xh, wih, woh);

  // QKV projection: (8192/128)*(3072/128) = 64*24 = 1536 blocks
  // = exactly 3 full rounds at 2 blocks/CU. Q pre-scaled by log2(e)/8.
  gemm128p_f16<true, true><<<1536, 256, 0, stream>>>(
      xh, wih, bi, qkvb, M, 3 * D_, D_);

  transpose_v<<<dim3(32, 64), 256, 0, stream>>>((const u16*)qkvb, (u16*)vT);

  attn_f16<<<dim3(16, 64), 256, 0, stream>>>(qkvb, vT, attn, causal);

  // out-proj: 64*8 = 512 blocks = exactly 1 full round at 2 blocks/CU.
  gemm128p_f16<false, false><<<512, 256, 0, stream>>>(
      attn, woh, bo, d_out, M, D_, D_);
}

// Round 7
// 294.584 us; speedup vs baseline: 1.0805x; 1.0805x over previous
//
#include <hip/hip_runtime.h>

typedef unsigned short u16;
typedef _Float16 h8 __attribute__((ext_vector_type(8)));
typedef __fp16 fp16x2 __attribute__((ext_vector_type(2)));
typedef float f32x4 __attribute__((ext_vector_type(4)));

constexpr int B_ = 4, S_ = 2048, D_ = 1024, H_ = 16;

// async global->LDS, 16B per lane; LDS dest = (wave-uniform base) + lane*16
__device__ __forceinline__ void async16(const void* g, void* l) {
  __builtin_amdgcn_global_load_lds(
      (const __attribute__((address_space(1))) void*)g,
      (__attribute__((address_space(3))) void*)l, 16, 0, 0);
}

// pack two f32 -> fp16x2 (RTZ) as a raw uint
__device__ __forceinline__ unsigned pk2(float a, float b) {
  union { fp16x2 h; unsigned u; } c;
  c.h = __builtin_amdgcn_cvt_pkrtz(a, b);
  return c.u;
}

// raw hardware exp2 (v_exp_f32), no ln2 multiply
__device__ __forceinline__ float fexp2(float x) {
#if __has_builtin(__builtin_amdgcn_exp2f)
  return __builtin_amdgcn_exp2f(x);
#else
  return exp2f(x);
#endif
}

// log2(e)/8: folded into the Q columns of the QKV GEMM epilogue (f32, before
// the single fp16 rounding -> same error structure as the exact-1/8 path).
#define QSCALE 0.18033688011112042f

// ---------------------------------------------------------------------------
// fp32 -> fp16 convert for all three tensors in ONE launch.
// Region split by blockIdx: x [0,8192), wi [8192,11264), wo [11264,12288).
// ---------------------------------------------------------------------------
__global__ __launch_bounds__(256) void cvt3_kernel(
    const float* __restrict__ x, const float* __restrict__ wi,
    const float* __restrict__ wo, _Float16* __restrict__ xh,
    _Float16* __restrict__ wih, _Float16* __restrict__ woh)
{
  const int bid = blockIdx.x;
  const float* src;
  _Float16* dst;
  int base;
  if (bid < 8192)       { src = x;  dst = xh;  base = bid; }
  else if (bid < 11264) { src = wi; dst = wih; base = bid - 8192; }
  else                  { src = wo; dst = woh; base = bid - 11264; }
  const int i = (base * 256 + threadIdx.x) * 4;
  const float4 v = *(const float4*)(src + i);
  uint2 o;
  o.x = pk2(v.x, v.y);
  o.y = pk2(v.z, v.w);
  *(uint2*)(dst + i) = o;
}

// ---------------------------------------------------------------------------
// 256xBN deep-pipelined GEMM, BN = BPW*64 (measured-best QKV structure, 91us).
// 512 threads = 8 waves (2m x 4n), wave tile 128 x (BN/4), acc[8][BPW].
// Frag-major LDS (zero bank conflicts). WRITE-BEHIND pipeline, prefetch
// distance 2, NO mid-loop vmcnt(0); boundary wait = counted vmcnt(4+BPW).
// Epilogue fusions:
//   SCALE_Q: Q columns (col<1024) scaled by log2(e)/8 (exp2-softmax).
//   FUSE_V : V columns (col>=2048) written TRANSPOSED straight to
//            vT[(b*1024 + col-2048)][s] (one 8B store per 4 rows) -- replaces
//            the separate transpose_v kernel and its 33MB of traffic.
// ---------------------------------------------------------------------------
template<bool OUT_HALF, int BPW, bool SCALE_Q, bool FUSE_V>
__global__ __launch_bounds__(512, 2) void gemm256d_f16(
    const _Float16* __restrict__ A, const _Float16* __restrict__ Bw,
    const float* __restrict__ bias, void* __restrict__ Cout,
    _Float16* __restrict__ vTout,
    int M, int N, int K)
{
  constexpr int BN = BPW * 64;
  constexpr int NBB = BN / 8;  // B frag-blocks per K-tile
  __shared__ __align__(16) _Float16 sA[2][16384];
  __shared__ __align__(16) _Float16 sB[2][NBB * 512];

  const int tid = threadIdx.x;
  const int lane = tid & 63, w = tid >> 6;   // 8 waves
  const int wm = w >> 2, wn = w & 3;         // 2 x 4 wave grid

  // XCD-bijective swizzle (gridDim.x % 8 == 0)
  const int id = blockIdx.x;
  const int cpx = gridDim.x >> 3;
  const int swz = (id & 7) * cpx + (id >> 3);
  const int nbx = N / BN;
  const int bx = swz % nbx, by = swz / nbx;
  const int m0 = by * 256, n0 = bx * BN;

  // Staging map: wave w owns A m-tiles {2w,2w+1} (4 loads) and B
  // frag-blocks {w*BPW .. w*BPW+BPW-1} (BPW loads).
  const int r15 = lane & 15, s4 = lane >> 4;
  const _Float16* gA[4];
  int loA[4];
#pragma unroll
  for (int j = 0; j < 4; ++j) {
    const int t = 2 * w + (j >> 1), kk = j & 1;
    gA[j] = A + (size_t)(m0 + 16 * t + r15) * K + kk * 32 + s4 * 8;
    loA[j] = (t * 2 + kk) * 512;
  }
  const _Float16* gB[BPW];
  int loB[BPW];
#pragma unroll
  for (int j = 0; j < BPW; ++j) {
    const int f = w * BPW + j, nt = f >> 1, kk = f & 1;
    gB[j] = Bw + (size_t)(n0 + 16 * nt + r15) * K + kk * 32 + s4 * 8;
    loB[j] = f * 512;
  }

  const f32x4 zf = {0.f, 0.f, 0.f, 0.f};
  f32x4 acc[8][BPW];
#pragma unroll
  for (int i = 0; i < 8; ++i)
#pragma unroll
    for (int j = 0; j < BPW; ++j) acc[i][j] = zf;

  // prologue: tiles 0 and 1 fully staged; retire tile 0's (4+BPW) loads
#pragma unroll
  for (int j = 0; j < 4; ++j) async16(gA[j], &sA[0][loA[j]]);
#pragma unroll
  for (int j = 0; j < BPW; ++j) async16(gB[j], &sB[0][loB[j]]);
#pragma unroll
  for (int j = 0; j < 4; ++j) async16(gA[j] + 64, &sA[1][loA[j]]);
#pragma unroll
  for (int j = 0; j < BPW; ++j) async16(gB[j] + 64, &sB[1][loB[j]]);
  if constexpr (BPW == 2)      asm volatile("s_waitcnt vmcnt(6)" ::: "memory");
  else if constexpr (BPW == 3) asm volatile("s_waitcnt vmcnt(7)" ::: "memory");
  else                         asm volatile("s_waitcnt vmcnt(8)" ::: "memory");
  __builtin_amdgcn_s_barrier();

  const int NT = K >> 6;
  int cur = 0;
  for (int kt = 0; kt < NT; ++kt) {
    const _Float16* pA = sA[cur];
    const _Float16* pB = sB[cur];
    _Float16* nA = sA[cur];  // write-behind: stage tile kt+2 into read buffer
    _Float16* nB = sB[cur];
    const bool st = (kt + 2 < NT);
    const int ko = (kt + 2) * 64;

    h8 fb[BPW][2];
#pragma unroll
    for (int p = 0; p < 4; ++p) {
      if (p == 0) {
#pragma unroll
        for (int nt = 0; nt < BPW; ++nt)
#pragma unroll
          for (int kk = 0; kk < 2; ++kk)
            fb[nt][kk] = *(const h8*)&pB[((wn * BPW + nt) * 2 + kk) * 512 + lane * 8];
      } else if (st) {
        if (p == 1) {
#pragma unroll
          for (int j = 0; j < BPW; ++j) async16(gB[j] + ko, &nB[loB[j]]);
        }
        if ((w & 3) == p - 1) {
#pragma unroll
          for (int j = 0; j < 4; ++j) async16(gA[j] + ko, &nA[loA[j]]);
        }
      }
      h8 fa[2][2];
#pragma unroll
      for (int i = 0; i < 2; ++i)
#pragma unroll
        for (int kk = 0; kk < 2; ++kk)
          fa[i][kk] = *(const h8*)&pA[((wm * 8 + 2 * p + i) * 2 + kk) * 512 + lane * 8];
      __builtin_amdgcn_s_setprio(1);
#pragma unroll
      for (int i = 0; i < 2; ++i)
#pragma unroll
        for (int nt = 0; nt < BPW; ++nt)
#pragma unroll
          for (int kk = 0; kk < 2; ++kk)
            acc[2 * p + i][nt] = __builtin_amdgcn_mfma_f32_16x16x32_f16(
                fa[i][kk], fb[nt][kk], acc[2 * p + i][nt], 0, 0, 0);
      __builtin_amdgcn_s_setprio(0);
      __builtin_amdgcn_s_barrier();  // phase-p closing barrier (staging license)
    }
    // waves with (w&3)==3: their A m-tiles freed only after phase 3
    if (st && (w & 3) == 3) {
#pragma unroll
      for (int j = 0; j < 4; ++j) async16(gA[j] + ko, &nA[loA[j]]);
    }
    if (kt + 1 < NT) {
      if (st) {  // retire tile kt+1's loads; tile kt+2's stay in flight
        if constexpr (BPW == 2)      asm volatile("s_waitcnt vmcnt(6)" ::: "memory");
        else if constexpr (BPW == 3) asm volatile("s_waitcnt vmcnt(7)" ::: "memory");
        else                         asm volatile("s_waitcnt vmcnt(8)" ::: "memory");
      } else {
        asm volatile("s_waitcnt vmcnt(0)" ::: "memory");
      }
      __builtin_amdgcn_s_barrier();  // boundary: all waves' next tile landed
    }
    cur ^= 1;
  }

  // ---- epilogue
  const int g = lane >> 4, cc = lane & 15;
#pragma unroll
  for (int nt = 0; nt < BPW; ++nt) {
    const int col = n0 + wn * (16 * BPW) + nt * 16 + cc;
    const float bv = bias[col];
    float qs = 1.0f;
    if constexpr (SCALE_Q) qs = (col < 1024) ? QSCALE : 1.0f;
#pragma unroll
    for (int mt = 0; mt < 8; ++mt) {
      const int rowb = m0 + wm * 128 + mt * 16 + g * 4;
      float vv[4];
#pragma unroll
      for (int r = 0; r < 4; ++r) {
        vv[r] = acc[mt][nt][r] + bv;
        if constexpr (SCALE_Q) vv[r] *= qs;
      }
      bool vcol = false;
      if constexpr (FUSE_V) vcol = (col >= 2048);
      if (vcol) {
        // V transposed: vT[(b*1024 + col-2048)][s], s = rowb&2047, b = rowb>>11.
        // 4 consecutive s -> one 8B store (RTN casts, identical numerics to
        // the old store+transpose path).
        union { _Float16 hx[4]; uint2 u; } pv;
#pragma unroll
        for (int r = 0; r < 4; ++r) pv.hx[r] = (_Float16)vv[r];
        *(uint2*)&vTout[((size_t)(((rowb >> 11) << 10) + (col - 2048)) << 11) + (rowb & 2047)] = pv.u;
      } else {
#pragma unroll
        for (int r = 0; r < 4; ++r) {
          if constexpr (OUT_HALF)
            ((_Float16*)Cout)[(size_t)(rowb + r) * N + col] = (_Float16)vv[r];
          else
            ((float*)Cout)[(size_t)(rowb + r) * N + col] = vv[r];
        }
      }
    }
  }
}

// ---------------------------------------------------------------------------
// 128x128x32 2-barrier GEMM (proven): out-proj (N=1024). 512 blocks, 3/CU.
// ---------------------------------------------------------------------------
template<bool OUT_HALF>
__global__ __launch_bounds__(256) void gemm_f16(
    const _Float16* __restrict__ A, const _Float16* __restrict__ Bw,
    const float* __restrict__ bias, void* __restrict__ Cout,
    int M, int N, int K)
{
  __shared__ __align__(16) _Float16 sA[4096];
  __shared__ __align__(16) _Float16 sB[4096];

  const int tid = threadIdx.x;
  const int lane = tid & 63, w = tid >> 6;
  const int wm = w & 1, wn = w >> 1;
  const int m0 = blockIdx.y * 128, n0 = blockIdx.x * 128;

  const int sr = 16 * w + (lane & 15);
  const int ss = lane >> 4;
  const _Float16* gA1 = A + (size_t)(m0 + sr) * K + 8 * ss;
  const _Float16* gA2 = gA1 + (size_t)64 * K;
  const _Float16* gB1 = Bw + (size_t)(n0 + sr) * K + 8 * ss;
  const _Float16* gB2 = gB1 + (size_t)64 * K;
  _Float16* lA1 = &sA[w * 512];
  _Float16* lA2 = &sA[(w + 4) * 512];
  _Float16* lB1 = &sB[w * 512];
  _Float16* lB2 = &sB[(w + 4) * 512];

  const f32x4 zf = {0.f, 0.f, 0.f, 0.f};
  f32x4 acc[4][4];
#pragma unroll
  for (int i = 0; i < 4; ++i)
#pragma unroll
    for (int j = 0; j < 4; ++j) acc[i][j] = zf;

  for (int k0 = 0; k0 < K; k0 += 32) {
    __syncthreads();
    async16(gA1 + k0, lA1);
    async16(gA2 + k0, lA2);
    async16(gB1 + k0, lB1);
    async16(gB2 + k0, lB2);
    __syncthreads();

    h8 fa[4], fb[4];
#pragma unroll
    for (int i = 0; i < 4; ++i) {
      fa[i] = *(const h8*)&sA[((wm * 4 + i) << 9) + (lane << 3)];
      fb[i] = *(const h8*)&sB[((wn * 4 + i) << 9) + (lane << 3)];
    }
#pragma unroll
    for (int i = 0; i < 4; ++i)
#pragma unroll
      for (int j = 0; j < 4; ++j)
        acc[i][j] = __builtin_amdgcn_mfma_f32_16x16x32_f16(fa[i], fb[j], acc[i][j], 0, 0, 0);
  }

  const int g = lane >> 4, cc = lane & 15;
#pragma unroll
  for (int j = 0; j < 4; ++j) {
    const int col = n0 + (wn * 4 + j) * 16 + cc;
    const float bv = bias[col];
#pragma unroll
    for (int i = 0; i < 4; ++i) {
      const int rowb = m0 + (wm * 4 + i) * 16 + g * 4;
#pragma unroll
      for (int r = 0; r < 4; ++r) {
        const float v = acc[i][j][r] + bv;
        if constexpr (OUT_HALF)
          ((_Float16*)Cout)[(size_t)(rowb + r) * N + col] = (_Float16)v;
        else
          ((float*)Cout)[(size_t)(rowb + r) * N + col] = v;
      }
    }
  }
}

// ---------------------------------------------------------------------------
// Flash attention fp16. Block = 128 q-rows of one (b,h), 4 waves, wave owns
// 32 q (m=2 tiles). S^T via mfma(kf,qf); sP aliases sQ. K/V/Q staged with
// global_load_lds width 16. LDS 34 KiB -> 4 blocks/CU.
// Q arrives PRE-SCALED by log2(e)/8 -> P = exp2(S) raw v_exp_f32.
// 1D grid + XCD swizzle: the 16 q-blocks sharing one bh's K/V land on ONE
// XCD (contiguous swz) -> K/V L2-resident per XCD instead of 8x refetch.
// ---------------------------------------------------------------------------
__global__ __launch_bounds__(256, 4) void attn_f16(
    const _Float16* __restrict__ qkv, const _Float16* __restrict__ vT,
    _Float16* __restrict__ attnO, const int* __restrict__ causal_ptr)
{
  __shared__ __align__(16) _Float16 sQP[9216];  // Q staging, then P (4w x 32 x 72)
  __shared__ __align__(16) _Float16 sK[4096];
  __shared__ __align__(16) _Float16 sV[4096];

  const int tid = threadIdx.x, lane = tid & 63, w = tid >> 6;
  const int q4 = lane >> 4, cc = lane & 15;
  // 1024 blocks: bijective XCD swizzle; consecutive swz (same bh) on one XCD
  const int id = blockIdx.x;
  const int swz = (id & 7) * 128 + (id >> 3);
  const int bh = swz >> 4, b = bh >> 4, h = bh & 15;
  const int q0 = (swz & 15) << 7;
  const int causal = causal_ptr[0];

  {
    const int rr = lane & 15, sc8 = lane >> 4;
#pragma unroll
    for (int tt = 0; tt < 2; ++tt) {
      const int t = 2 * w + tt;
#pragma unroll
      for (int sh = 0; sh < 2; ++sh) {
        const _Float16* g = qkv + (size_t)(b * S_ + q0 + 16 * t + rr) * 3072 + h * 64 + 8 * (4 * sh + sc8);
        async16(g, &sQP[t * 1024 + sh * 512]);
      }
    }
  }
  __syncthreads();  // Q landed

  // Q frags (already carry the log2(e)/8 score scale from the GEMM epilogue)
  h8 qf[2][2];
#pragma unroll
  for (int m = 0; m < 2; ++m)
#pragma unroll
    for (int kk = 0; kk < 2; ++kk)
      qf[m][kk] = *(const h8*)&sQP[((2 * w + m) << 10) + (kk << 9) + (lane << 3)];

  h8 ones;
#pragma unroll
  for (int i = 0; i < 8; ++i) ones[i] = (_Float16)1.0f;

  const _Float16* gK = qkv + (size_t)(b * S_ + 16 * w + (lane & 15)) * 3072 + 1024 + h * 64 + 8 * (lane >> 4);
  const _Float16* gV = vT + (size_t)(bh * 64 + 16 * w + (lane & 15)) * S_ + 8 * (lane >> 4);
  _Float16* lK0 = &sK[w * 1024];
  _Float16* lV0 = &sV[w * 1024];

  const int wp = w * 2304;

  const f32x4 zf = {0.f, 0.f, 0.f, 0.f};
  f32x4 oa[2][4], lac[2];
#pragma unroll
  for (int m = 0; m < 2; ++m) {
    lac[m] = zf;
#pragma unroll
    for (int nt = 0; nt < 4; ++nt) oa[m][nt] = zf;
  }

  for (int j0 = 0; j0 < S_; j0 += 64) {
    if (causal && j0 > q0 + 127) break;
    __syncthreads();
    async16(gK + (size_t)j0 * 3072, lK0);
    async16(gK + (size_t)j0 * 3072 + 32, lK0 + 512);
    async16(gV + j0, lV0);
    async16(gV + j0 + 32, lV0 + 512);
    __syncthreads();

    f32x4 sc[2][4];
    __builtin_amdgcn_s_setprio(1);
#pragma unroll
    for (int nt = 0; nt < 4; ++nt) {
      const h8 kf0 = *(const h8*)&sK[(nt << 10) + (lane << 3)];
      const h8 kf1 = *(const h8*)&sK[(nt << 10) + 512 + (lane << 3)];
#pragma unroll
      for (int m = 0; m < 2; ++m) {
        sc[m][nt] = __builtin_amdgcn_mfma_f32_16x16x32_f16(kf0, qf[m][0], zf, 0, 0, 0);
        sc[m][nt] = __builtin_amdgcn_mfma_f32_16x16x32_f16(kf1, qf[m][1], sc[m][nt], 0, 0, 0);
      }
    }
    __builtin_amdgcn_s_setprio(0);

    if (causal) {
#pragma unroll
      for (int m = 0; m < 2; ++m)
#pragma unroll
        for (int nt = 0; nt < 4; ++nt)
#pragma unroll
          for (int r = 0; r < 4; ++r)
            if ((j0 + nt * 16 + q4 * 4 + r) > (q0 + 32 * w + m * 16 + cc))
              sc[m][nt][r] = -1.0e30f;
    }

    // P = exp2(S): scores arrive in log2 units; raw v_exp_f32, no multiply
#pragma unroll
    for (int m = 0; m < 2; ++m)
#pragma unroll
      for (int nt = 0; nt < 4; ++nt) {
        uint2 pk;
        pk.x = pk2(fexp2(sc[m][nt][0]), fexp2(sc[m][nt][1]));
        pk.y = pk2(fexp2(sc[m][nt][2]), fexp2(sc[m][nt][3]));
        *(uint2*)&sQP[wp + (m * 16 + cc) * 72 + nt * 16 + q4 * 4] = pk;
      }

    asm volatile("s_waitcnt lgkmcnt(0)" ::: "memory");

    h8 pf[2][2];
#pragma unroll
    for (int m = 0; m < 2; ++m)
#pragma unroll
      for (int kk = 0; kk < 2; ++kk)
        pf[m][kk] = *(const h8*)&sQP[wp + (m * 16 + cc) * 72 + kk * 32 + q4 * 8];

    __builtin_amdgcn_s_setprio(1);
#pragma unroll
    for (int m = 0; m < 2; ++m) {
      lac[m] = __builtin_amdgcn_mfma_f32_16x16x32_f16(pf[m][0], ones, lac[m], 0, 0, 0);
      lac[m] = __builtin_amdgcn_mfma_f32_16x16x32_f16(pf[m][1], ones, lac[m], 0, 0, 0);
    }
#pragma unroll
    for (int nt = 0; nt < 4; ++nt) {
      const h8 vf0 = *(const h8*)&sV[(nt << 10) + (lane << 3)];
      const h8 vf1 = *(const h8*)&sV[(nt << 10) + 512 + (lane << 3)];
#pragma unroll
      for (int m = 0; m < 2; ++m) {
        oa[m][nt] = __builtin_amdgcn_mfma_f32_16x16x32_f16(pf[m][0], vf0, oa[m][nt], 0, 0, 0);
        oa[m][nt] = __builtin_amdgcn_mfma_f32_16x16x32_f16(pf[m][1], vf1, oa[m][nt], 0, 0, 0);
      }
    }
    __builtin_amdgcn_s_setprio(0);
  }

#pragma unroll
  for (int m = 0; m < 2; ++m) {
    float inv[4];
#pragma unroll
    for (int r = 0; r < 4; ++r) inv[r] = 1.0f / lac[m][r];
#pragma unroll
    for (int nt = 0; nt < 4; ++nt) {
      const int col = h * 64 + nt * 16 + cc;
#pragma unroll
      for (int r = 0; r < 4; ++r) {
        const int row = b * S_ + q0 + 32 * w + m * 16 + q4 * 4 + r;
        attnO[(size_t)row * D_ + col] = (_Float16)(oa[m][nt][r] * inv[r]);
      }
    }
  }
}

// ---------------------------------------------------------------------------
extern "C" void kernel_launch(void* const* d_in, const int* in_sizes, int n_in,
                              void* d_out, int out_size, void* d_ws, size_t ws_size,
                              hipStream_t stream)
{
  const float* x  = (const float*)d_in[0];
  const float* wi = (const float*)d_in[1];
  const float* bi = (const float*)d_in[2];
  const float* wo = (const float*)d_in[3];
  const float* bo = (const float*)d_in[4];
  const int* causal = (const int*)d_in[5];

  _Float16* xh   = (_Float16*)d_ws;       // 8192*1024
  _Float16* wih  = xh + 8388608;          // 3072*1024
  _Float16* woh  = wih + 3145728;         // 1024*1024
  _Float16* qkvb = woh + 1048576;         // 8192*3072 (V region unused now)
  _Float16* vT   = qkvb + 25165824;       // 4096*2048
  _Float16* attn = vT + 8388608;          // 8192*1024

  const int M = B_ * S_;  // 8192

  cvt3_kernel<<<12288, 256, 0, stream>>>(x, wi, wo, xh, wih, woh);

  // QKV projection: BN=192 -> 32*16 = 512 blocks = exactly 2 full rounds.
  // Q pre-scaled by log2(e)/8; V columns written transposed to vT (fused).
  gemm256d_f16<true, 3, true, true><<<512, 512, 0, stream>>>(
      xh, wih, bi, qkvb, vT, M, 3 * D_, D_);

  attn_f16<<<1024, 256, 0, stream>>>(qkvb, vT, attn, causal);

  // out-proj: 128^2 kernel, 512 blocks, 3 blocks/CU.
  gemm_f16<false><<<dim3(8, 64), 256, 0, stream>>>(
      attn, woh, bo, d_out, M, D_, D_);
}